// Round 1
// baseline (362.708 us; speedup 1.0000x reference)
//
#include <hip/hip_runtime.h>

// Soft differentiable rasterizer, forward only. Two-kernel structure.
// R9 -> R10: per-(tile,slot) EDGE-ACTIVITY MASKS. Raster was trans-pipe
// bound (~88us floor from 12 exp2 per slot-pixel; VALUBusy 66%, HBM 6%).
// u = A*gy+B*gx+C is linear -> over a 32x2 tile u in [u_c-R, u_c+R],
// R = |A|*0.5/128 + |B|*15.5/128. Setup now classifies each listed
// (tile,slot): edge inactive (factor~1) if u_max < -18; slot dead for the
// tile if any edge u_min > +18 (cov <= 2^-18). Packed list entry
// slot | mask<<8 | dead<<20 (u32). Raster: uniform-branch skip of dead
// entries, cov=1 fast path on empty mask, else scalar loop over set bits
// (1 exp2 per ACTIVE edge). Error added <= ~5e-5 (budget: absmax 9.8e-4).
// Design (from R8/R9): 32x2 px tiles, setup cull via per-edge line form,
// pos-first packing, strided line-form loop (R9 bugfix), raster scalar
// coefficient cache, front-to-back T, wave exit at T < 2e-3.

#define HH 128
#define WW 128
#define NN 128
#define KK 12
#define STPB 1024
#define RTPB 256
#define STATE_SZ (NN * KK * 2 + NN) // 3200
#define CULL_U 15.0f
#define COEF_STRIDE 40              // floats per slot: A[12] B[12] C[12] gc[4]
#define MASK_TH 18.0f               // exp2-units activity threshold

typedef float f2 __attribute__((ext_vector_type(2)));

__global__ __launch_bounds__(STPB) void setup_kernel(
    const float* __restrict__ traj,
    const float* __restrict__ colors,
    const float* __restrict__ alpha,
    const float* __restrict__ zval,
    const void*  __restrict__ csg_raw,
    float* __restrict__ g_coef,         // [T][128][40]
    int* __restrict__ g_cnt,            // [T][256]
    unsigned int* __restrict__ g_list)  // [T][256][128] packed u32
{
    __shared__ __align__(16) float s_coef[NN][COEF_STRIDE];       // 20.5 KB
    __shared__ __align__(16) float2 s_pq[NN][KK];                 // 12.3 KB
    __shared__ float s_state[STATE_SZ];                           // 12.8 KB
    __shared__ float s_orient[NN];
    __shared__ float s_z[NN];
    __shared__ int   s_slot2prim[NN];
    __shared__ int   s_npos[NN], s_nneg[NN];
    __shared__ unsigned long long s_qbits[HH][4][2];              // 8 KB
    __shared__ unsigned char s_list[4 * (HH / 2)][NN];            // 32 KB
    __shared__ int s_cnt[4 * (HH / 2)];
    __shared__ int s_mode;

    const int frame = blockIdx.x;
    const int tid   = threadIdx.x;
    const float* st = traj + (size_t)frame * STATE_SZ;

    // ---- stage + csg layout detect + counter init ----
    for (int i = tid; i < STATE_SZ; i += STPB) s_state[i] = st[i];
    if (tid < NN) { s_z[tid] = zval[tid]; s_npos[tid] = 0; s_nneg[tid] = 0; }
    if (tid == 0) {
        const unsigned char* b = (const unsigned char*)csg_raw;
        const unsigned int*  w = (const unsigned int*)csg_raw;
        int mode = 0; // int32
        bool words01 = true;
        for (int i = 0; i < 32; i++) if (w[i] > 1u) { words01 = false; break; }
        if (!words01) {
            bool bytes01 = true;
            for (int i = 0; i < 128; i++) if (b[i] > 1) { bytes01 = false; break; }
            mode = bytes01 ? 1 : 2;
        }
        s_mode = mode;
    }
    __syncthreads();

    // ---- per-prim: orient, g = alpha*sigmoid(alive), z-rank -> slot ----
    if (tid < NN) {
        const int n = tid;
        float area2 = 0.f;
        #pragma unroll
        for (int k = 0; k < KK; k++) {
            int k1 = (k + 1) % KK;
            float v0x = s_state[(n * KK + k)  * 2 + 0];
            float v0y = s_state[(n * KK + k)  * 2 + 1];
            float v1x = s_state[(n * KK + k1) * 2 + 0];
            float v1y = s_state[(n * KK + k1) * 2 + 1];
            area2 += v0x * v1y - v1x * v0y;
        }
        float orient = (area2 > 0.f) ? 1.f : ((area2 < 0.f) ? -1.f : 0.f);
        s_orient[n] = orient;

        float alive = s_state[NN * KK * 2 + n];
        float g = alpha[n] / (1.f + __expf(-alive));

        float zn = s_z[n];
        int rank = 0;
        for (int j = 0; j < NN; j++) {
            float zj = s_z[j];
            rank += (zj < zn || (zj == zn && j < n)) ? 1 : 0;
        }
        int slot = (NN - 1) - rank; // slot 0 = frontmost (largest z)
        s_slot2prim[slot] = n;

        int mode = s_mode;
        int sub;
        if (mode == 0)      sub = ((const int*)csg_raw)[n] != 0;
        else if (mode == 1) sub = ((const unsigned char*)csg_raw)[n] != 0;
        else                sub = ((const float*)csg_raw)[n] != 0.f;
        float cs = sub ? 0.f : 1.f;
        s_coef[slot][36] = g;
        s_coef[slot][37] = colors[n * 3 + 0] * cs;
        s_coef[slot][38] = colors[n * 3 + 1] * cs;
        s_coef[slot][39] = colors[n * 3 + 2] * cs;
    }
    __syncthreads();

    // ---- edge coefficients (slot-ordered SoA) ----
    const float QSCALE = 100.0f * 1.4426950408889634f;
    for (int idx = tid; idx < NN * KK; idx += STPB) {
        int slot = idx / KK;
        int k    = idx - slot * KK;
        int n    = s_slot2prim[slot];
        int k1   = (k + 1) % KK;
        float v0x = s_state[(n * KK + k)  * 2 + 0];
        float v0y = s_state[(n * KK + k)  * 2 + 1];
        float v1x = s_state[(n * KK + k1) * 2 + 0];
        float v1y = s_state[(n * KK + k1) * 2 + 1];
        float ex = v1x - v0x, ey = v1y - v0y;
        float q  = -s_orient[n] * QSCALE;
        s_coef[slot][0  + k] = q * ex;                      // A
        s_coef[slot][12 + k] = -q * ey;                     // B
        s_coef[slot][24 + k] = -q * (ex * v0y - ey * v0x);  // C
    }
    __syncthreads();

    // ---- line form per edge: x-constraint t(gy) = Q*gy + P ----
    // B>0: x <= t (+SLACK); B<0: x >= t (stored negated: -x <= -t, +SLACK);
    // B==0: no x-constraint -> neg-bucket entry with t' = +1e30 (never binds).
    // Pos edges packed first (k < npos). STRIDED LOOP (R8 bug: bare if).
    const float SLACK = 0.01f;
    for (int idx = tid; idx < NN * KK; idx += STPB) {
        int slot = idx / KK;
        int k    = idx - slot * KK;
        (void)k;
        float A = s_coef[slot][idx - slot * KK];
        float B = s_coef[slot][12 + (idx - slot * KK)];
        float C = s_coef[slot][24 + (idx - slot * KK)];
        float rcpB = __builtin_amdgcn_rcpf(B);
        float Praw = (CULL_U - C) * rcpB;
        float Qraw = -A * rcpB;
        if (B > 0.f) {
            int i = atomicAdd(&s_npos[slot], 1);
            s_pq[slot][i] = make_float2(Qraw, Praw + SLACK);
        } else if (B < 0.f) {
            int i = atomicAdd(&s_nneg[slot], 1);
            s_pq[slot][(KK - 1) - i] = make_float2(-Qraw, -Praw + SLACK);
        } else { // B == 0: x-independent edge; conservatively no constraint
            int i = atomicAdd(&s_nneg[slot], 1);
            s_pq[slot][(KK - 1) - i] = make_float2(0.f, 1e30f);
        }
    }
    __syncthreads();

    // ---- joint interval cull; 4 x-quarter keep masks per row ----
    // wave covers one row (r const) x 64 slots (s = s0 + lane).
    const float GX_LO = 0.5f / WW;
    const float GX_HI = (WW - 0.5f) / WW;
    for (int j = 0; j < (HH * NN) / STPB; j++) {     // 16 iters
        int idx = j * STPB + tid;
        int r = idx >> 7, s = idx & (NN - 1);
        float gyr = (r + 0.5f) * (1.0f / HH);
        int npos = s_npos[s];
        const float4* pq4 = (const float4*)&s_pq[s][0];
        float y1 = 1e30f, y2 = 1e30f;
        #pragma unroll
        for (int h = 0; h < KK / 2; h++) {
            float4 v = pq4[h];                       // {Q,P,Q,P}
            int k0 = 2 * h, k1 = 2 * h + 1;
            float t0 = fmaf(v.x, gyr, v.y);
            float t1 = fmaf(v.z, gyr, v.w);
            bool p0 = k0 < npos, p1 = k1 < npos;
            y1 = fminf(y1, p0 ? t0 : 1e30f);
            y2 = fminf(y2, p0 ? 1e30f : t0);
            y1 = fminf(y1, p1 ? t1 : 1e30f);
            y2 = fminf(y2, p1 ? 1e30f : t1);
        }
        float xhi = fminf(y1, GX_HI);
        float xlo = fmaxf(-y2, GX_LO);
        bool ne = (xlo <= xhi);
        #pragma unroll
        for (int q = 0; q < 4; q++) {
            float qlo = (q * 32 + 0.5f) * (1.0f / WW);
            float qhi = (q * 32 + 31.5f) * (1.0f / WW);
            unsigned long long m = __ballot(ne && (xlo <= qhi) && (xhi >= qlo));
            if ((tid & 63) == 0) s_qbits[r][q][(s >= 64) ? 1 : 0] = m;
        }
    }
    __syncthreads();

    // ---- compaction: thread = tile (row-pair x x-quarter), slot-ascending ----
    if (tid < 4 * (HH / 2)) {
        int rp = tid >> 2, q = tid & 3;
        unsigned long long b0 = s_qbits[2 * rp][q][0] | s_qbits[2 * rp + 1][q][0];
        unsigned long long b1 = s_qbits[2 * rp][q][1] | s_qbits[2 * rp + 1][q][1];
        int n = 0;
        while (b0) { int k = __builtin_ctzll(b0); b0 &= b0 - 1; s_list[tid][n++] = (unsigned char)k; }
        while (b1) { int k = __builtin_ctzll(b1); b1 &= b1 - 1; s_list[tid][n++] = (unsigned char)(64 + k); }
        s_cnt[tid] = n;
    }
    __syncthreads();

    // ---- per-(tile,entry) edge-activity mask; writes packed u32 list ----
    // u over tile = u_c +- R exactly (linear). Inactive edge: u_max < -TH
    // (factor within 2^-TH of 1). Dead slot: any edge u_min > +TH
    // (cov <= 2^-TH over whole tile).
    {
        unsigned int* dstl = g_list + (size_t)frame * (256 * NN);
        const float DY = 0.5f / HH, DX = 15.5f / WW;
        for (int idx = tid; idx < 256 * NN; idx += STPB) {  // 32 iters
            int tile = idx >> 7;
            int i    = idx & (NN - 1);
            if (i >= s_cnt[tile]) continue;
            int slot = s_list[tile][i];
            int rp = tile >> 2, qq = tile & 3;
            float gyc = (2 * rp + 1) * (1.0f / HH);
            float gxc = (32 * qq + 16) * (1.0f / WW);
            unsigned m = 0;
            bool dead = false;
            #pragma unroll
            for (int k = 0; k < KK; k++) {
                float A = s_coef[slot][k];
                float B = s_coef[slot][12 + k];
                float C = s_coef[slot][24 + k];
                float u = fmaf(A, gyc, fmaf(B, gxc, C));
                float R = fmaf(__builtin_fabsf(A), DY, __builtin_fabsf(B) * DX);
                if (u + R > -MASK_TH) m |= (1u << k);
                if (u - R >  MASK_TH) dead = true;
            }
            dstl[tile * NN + i] = (unsigned)slot | (m << 8) | (dead ? (1u << 20) : 0u);
        }
    }

    // ---- copy out ----
    {
        float* dstc = g_coef + (size_t)frame * (NN * COEF_STRIDE);
        const float* srcc = &s_coef[0][0];
        for (int i = tid; i < NN * COEF_STRIDE; i += STPB) dstc[i] = srcc[i];
        if (tid < 256) g_cnt[frame * 256 + tid] = s_cnt[tid];
    }
}

struct F3 { float x, y, z; };

__global__ __launch_bounds__(RTPB) void raster_kernel(
    const float* __restrict__ g_coef,
    const int* __restrict__ g_cnt,
    const unsigned int* __restrict__ g_list,
    float* __restrict__ out)
{
    __shared__ unsigned int s_wlist[4][NN];   // 2 KB

    const int tid   = threadIdx.x;
    const int wv    = __builtin_amdgcn_readfirstlane(tid >> 6);
    const int lane  = tid & 63;
    const int frame = blockIdx.y;
    const int tile  = blockIdx.x * 4 + wv;  // 0..255
    const int rp    = tile >> 2;            // row pair
    const int q     = tile & 3;             // x quarter

    // stage this wave's survivor list into its private LDS strip
    const unsigned int* lst = g_list + ((size_t)frame * 256 + tile) * NN;
    ((uint2*)&s_wlist[wv][0])[lane] = ((const uint2*)lst)[lane];
    const int cnt = g_cnt[frame * 256 + tile]; // uniform -> s_load

    const int lx  = lane & 31, ly = lane >> 5;
    const int px  = q * 32 + lx;
    const int row = rp * 2 + ly;
    const float gy = (row + 0.5f) * (1.0f / HH);
    const float gx = (px  + 0.5f) * (1.0f / WW);

    const float* cfr = g_coef + (size_t)frame * (NN * COEF_STRIDE);

    float Tt = 1.f, rr = 0.f, gg = 0.f, bb = 0.f;
    for (int i = 0; i < cnt; i++) {
        unsigned e = (unsigned)__builtin_amdgcn_readfirstlane((int)s_wlist[wv][i]);
        if (e & (1u << 20)) continue;          // dead for this tile (cov<=2^-18)
        int slot = (int)(e & 0xFFu);
        unsigned m = (e >> 8) & 0xFFFu;
        const float* cf = cfr + slot * COEF_STRIDE; // uniform addr -> scalar loads

        float cov;
        if (m == 0u) {
            cov = 1.f;                          // all edges saturated inside
        } else {
            float qp = 1.f;
            do {                                // uniform scalar loop over set bits
                int k = __builtin_ctz(m); m &= m - 1u;
                float u = fmaf(cf[12 + k], gx, fmaf(cf[k], gy, cf[24 + k]));
                u = fmaxf(u, -100.f);           // exp2 underflow guard (inf*0=NaN)
                qp = fmaf(qp, __builtin_amdgcn_exp2f(u), qp); // qp *= 1 + 2^u
            } while (m);
            cov = __builtin_amdgcn_rcpf(qp);
        }

        float a = cov * cf[36];
        float w = a * Tt;
        rr = fmaf(w, cf[37], rr);
        gg = fmaf(w, cf[38], gg);
        bb = fmaf(w, cf[39], bb);
        Tt = fmaf(-a, Tt, Tt);

        if (!__any(Tt > 2e-3f)) break;   // residual <= T < 2e-3
    }

    size_t o = ((size_t)frame * (HH * WW) + (size_t)row * WW + px) * 3;
    *(F3*)(out + o) = F3{rr, gg, bb};    // coalesced dwordx3 per row segment
}

extern "C" void kernel_launch(void* const* d_in, const int* in_sizes, int n_in,
                              void* d_out, int out_size, void* d_ws, size_t ws_size,
                              hipStream_t stream) {
    const float* traj   = (const float*)d_in[0];
    const float* colors = (const float*)d_in[1];
    const float* alpha  = (const float*)d_in[2];
    const float* zval   = (const float*)d_in[3];
    const void*  csg    = d_in[4];
    float* out = (float*)d_out;

    const int T = in_sizes[0] / STATE_SZ; // 192

    size_t coef_sz = (size_t)T * NN * COEF_STRIDE * sizeof(float);  // 3.93 MB
    size_t cnt_sz  = (size_t)T * 256 * sizeof(int);                 // 0.20 MB
    float* g_coef = (float*)d_ws;
    int*   g_cnt  = (int*)((char*)d_ws + coef_sz);
    unsigned int* g_list = (unsigned int*)((char*)d_ws + coef_sz + cnt_sz); // 25.2 MB

    setup_kernel<<<T, STPB, 0, stream>>>(traj, colors, alpha, zval, csg,
                                         g_coef, g_cnt, g_list);
    dim3 grid(256 / 4, T); // 64 x 192, wave = one 32x2 tile
    raster_kernel<<<grid, RTPB, 0, stream>>>(g_coef, g_cnt, g_list, out);
}

// Round 2
// 284.719 us; speedup vs baseline: 1.2739x; 1.2739x over previous
//
#include <hip/hip_runtime.h>

// Soft differentiable rasterizer, forward only. Two-kernel structure.
// R10 -> R11: mask idea kept, execution structure fixed.
// R10 post-mortem: (a) raster ctz-loop did a SERIAL dependent s_load per
// active bit (~150-200cy L2 latency each, unhidden at ~4 waves/SIMD) ->
// 242us, VALUBusy 39% (latency-bound). (b) setup mask phase read
// s_coef[slot][k] with slot per-lane at stride 40 -> 8-way LDS bank
// conflict (40%32=8) -> ~+40us setup.
// R11: (a) PAIR-granular mask (6 bits). Per slot: batch-load gc + all 36
// coefs up front (uniform s_loads, R9 style), compute all 6 u-pairs
// unconditionally (full-rate fma), pin them with empty asm so loads can't
// sink into branches, then 6 UNIFORM branches holding only max/exp2/fma.
// Active pairs computed exactly -> error budget unchanged vs R9.
// pm==0 fast path skips everything. (b) LDS coef stride padded to 41
// (gcd(41,32)=1, conflict-free); global stride stays 40.
// Design (from R8/R9): 32x2 px tiles, setup cull via per-edge line form,
// pos-first packing, strided line-form loop, raster scalar coefficient
// cache, front-to-back T, wave exit at T < 2e-3.

#define HH 128
#define WW 128
#define NN 128
#define KK 12
#define STPB 1024
#define RTPB 256
#define STATE_SZ (NN * KK * 2 + NN) // 3200
#define CULL_U 15.0f
#define COEF_STRIDE 40              // floats per slot in GLOBAL: A[12] B[12] C[12] gc[4]
#define COEF_LSTR 41                // LDS stride (padded, conflict-free)
#define MASK_TH 18.0f               // exp2-units activity threshold

typedef float f2 __attribute__((ext_vector_type(2)));

__global__ __launch_bounds__(STPB) void setup_kernel(
    const float* __restrict__ traj,
    const float* __restrict__ colors,
    const float* __restrict__ alpha,
    const float* __restrict__ zval,
    const void*  __restrict__ csg_raw,
    float* __restrict__ g_coef,         // [T][128][40]
    int* __restrict__ g_cnt,            // [T][256]
    unsigned int* __restrict__ g_list)  // [T][256][128] packed u32
{
    __shared__ __align__(16) float s_coef[NN][COEF_LSTR];         // 21 KB
    __shared__ __align__(16) float2 s_pq[NN][KK];                 // 12.3 KB
    __shared__ float s_state[STATE_SZ];                           // 12.8 KB
    __shared__ float s_orient[NN];
    __shared__ float s_z[NN];
    __shared__ int   s_slot2prim[NN];
    __shared__ int   s_npos[NN], s_nneg[NN];
    __shared__ unsigned long long s_qbits[HH][4][2];              // 8 KB
    __shared__ unsigned char s_list[4 * (HH / 2)][NN];            // 32 KB
    __shared__ int s_cnt[4 * (HH / 2)];
    __shared__ int s_mode;

    const int frame = blockIdx.x;
    const int tid   = threadIdx.x;
    const float* st = traj + (size_t)frame * STATE_SZ;

    // ---- stage + csg layout detect + counter init ----
    for (int i = tid; i < STATE_SZ; i += STPB) s_state[i] = st[i];
    if (tid < NN) { s_z[tid] = zval[tid]; s_npos[tid] = 0; s_nneg[tid] = 0; }
    if (tid == 0) {
        const unsigned char* b = (const unsigned char*)csg_raw;
        const unsigned int*  w = (const unsigned int*)csg_raw;
        int mode = 0; // int32
        bool words01 = true;
        for (int i = 0; i < 32; i++) if (w[i] > 1u) { words01 = false; break; }
        if (!words01) {
            bool bytes01 = true;
            for (int i = 0; i < 128; i++) if (b[i] > 1) { bytes01 = false; break; }
            mode = bytes01 ? 1 : 2;
        }
        s_mode = mode;
    }
    __syncthreads();

    // ---- per-prim: orient, g = alpha*sigmoid(alive), z-rank -> slot ----
    if (tid < NN) {
        const int n = tid;
        float area2 = 0.f;
        #pragma unroll
        for (int k = 0; k < KK; k++) {
            int k1 = (k + 1) % KK;
            float v0x = s_state[(n * KK + k)  * 2 + 0];
            float v0y = s_state[(n * KK + k)  * 2 + 1];
            float v1x = s_state[(n * KK + k1) * 2 + 0];
            float v1y = s_state[(n * KK + k1) * 2 + 1];
            area2 += v0x * v1y - v1x * v0y;
        }
        float orient = (area2 > 0.f) ? 1.f : ((area2 < 0.f) ? -1.f : 0.f);
        s_orient[n] = orient;

        float alive = s_state[NN * KK * 2 + n];
        float g = alpha[n] / (1.f + __expf(-alive));

        float zn = s_z[n];
        int rank = 0;
        for (int j = 0; j < NN; j++) {
            float zj = s_z[j];
            rank += (zj < zn || (zj == zn && j < n)) ? 1 : 0;
        }
        int slot = (NN - 1) - rank; // slot 0 = frontmost (largest z)
        s_slot2prim[slot] = n;

        int mode = s_mode;
        int sub;
        if (mode == 0)      sub = ((const int*)csg_raw)[n] != 0;
        else if (mode == 1) sub = ((const unsigned char*)csg_raw)[n] != 0;
        else                sub = ((const float*)csg_raw)[n] != 0.f;
        float cs = sub ? 0.f : 1.f;
        s_coef[slot][36] = g;
        s_coef[slot][37] = colors[n * 3 + 0] * cs;
        s_coef[slot][38] = colors[n * 3 + 1] * cs;
        s_coef[slot][39] = colors[n * 3 + 2] * cs;
    }
    __syncthreads();

    // ---- edge coefficients (slot-ordered SoA) ----
    const float QSCALE = 100.0f * 1.4426950408889634f;
    for (int idx = tid; idx < NN * KK; idx += STPB) {
        int slot = idx / KK;
        int k    = idx - slot * KK;
        int n    = s_slot2prim[slot];
        int k1   = (k + 1) % KK;
        float v0x = s_state[(n * KK + k)  * 2 + 0];
        float v0y = s_state[(n * KK + k)  * 2 + 1];
        float v1x = s_state[(n * KK + k1) * 2 + 0];
        float v1y = s_state[(n * KK + k1) * 2 + 1];
        float ex = v1x - v0x, ey = v1y - v0y;
        float q  = -s_orient[n] * QSCALE;
        s_coef[slot][0  + k] = q * ex;                      // A
        s_coef[slot][12 + k] = -q * ey;                     // B
        s_coef[slot][24 + k] = -q * (ex * v0y - ey * v0x);  // C
    }
    __syncthreads();

    // ---- line form per edge: x-constraint t(gy) = Q*gy + P ----
    // B>0: x <= t (+SLACK); B<0: x >= t (stored negated: -x <= -t, +SLACK);
    // B==0: no x-constraint -> neg-bucket entry with t' = +1e30 (never binds).
    // Pos edges packed first (k < npos). STRIDED LOOP (R8 bug: bare if).
    const float SLACK = 0.01f;
    for (int idx = tid; idx < NN * KK; idx += STPB) {
        int slot = idx / KK;
        int k    = idx - slot * KK;
        (void)k;
        float A = s_coef[slot][idx - slot * KK];
        float B = s_coef[slot][12 + (idx - slot * KK)];
        float C = s_coef[slot][24 + (idx - slot * KK)];
        float rcpB = __builtin_amdgcn_rcpf(B);
        float Praw = (CULL_U - C) * rcpB;
        float Qraw = -A * rcpB;
        if (B > 0.f) {
            int i = atomicAdd(&s_npos[slot], 1);
            s_pq[slot][i] = make_float2(Qraw, Praw + SLACK);
        } else if (B < 0.f) {
            int i = atomicAdd(&s_nneg[slot], 1);
            s_pq[slot][(KK - 1) - i] = make_float2(-Qraw, -Praw + SLACK);
        } else { // B == 0: x-independent edge; conservatively no constraint
            int i = atomicAdd(&s_nneg[slot], 1);
            s_pq[slot][(KK - 1) - i] = make_float2(0.f, 1e30f);
        }
    }
    __syncthreads();

    // ---- joint interval cull; 4 x-quarter keep masks per row ----
    // wave covers one row (r const) x 64 slots (s = s0 + lane).
    const float GX_LO = 0.5f / WW;
    const float GX_HI = (WW - 0.5f) / WW;
    for (int j = 0; j < (HH * NN) / STPB; j++) {     // 16 iters
        int idx = j * STPB + tid;
        int r = idx >> 7, s = idx & (NN - 1);
        float gyr = (r + 0.5f) * (1.0f / HH);
        int npos = s_npos[s];
        const float4* pq4 = (const float4*)&s_pq[s][0];
        float y1 = 1e30f, y2 = 1e30f;
        #pragma unroll
        for (int h = 0; h < KK / 2; h++) {
            float4 v = pq4[h];                       // {Q,P,Q,P}
            int k0 = 2 * h, k1 = 2 * h + 1;
            float t0 = fmaf(v.x, gyr, v.y);
            float t1 = fmaf(v.z, gyr, v.w);
            bool p0 = k0 < npos, p1 = k1 < npos;
            y1 = fminf(y1, p0 ? t0 : 1e30f);
            y2 = fminf(y2, p0 ? 1e30f : t0);
            y1 = fminf(y1, p1 ? t1 : 1e30f);
            y2 = fminf(y2, p1 ? 1e30f : t1);
        }
        float xhi = fminf(y1, GX_HI);
        float xlo = fmaxf(-y2, GX_LO);
        bool ne = (xlo <= xhi);
        #pragma unroll
        for (int q = 0; q < 4; q++) {
            float qlo = (q * 32 + 0.5f) * (1.0f / WW);
            float qhi = (q * 32 + 31.5f) * (1.0f / WW);
            unsigned long long m = __ballot(ne && (xlo <= qhi) && (xhi >= qlo));
            if ((tid & 63) == 0) s_qbits[r][q][(s >= 64) ? 1 : 0] = m;
        }
    }
    __syncthreads();

    // ---- compaction: thread = tile (row-pair x x-quarter), slot-ascending ----
    if (tid < 4 * (HH / 2)) {
        int rp = tid >> 2, q = tid & 3;
        unsigned long long b0 = s_qbits[2 * rp][q][0] | s_qbits[2 * rp + 1][q][0];
        unsigned long long b1 = s_qbits[2 * rp][q][1] | s_qbits[2 * rp + 1][q][1];
        int n = 0;
        while (b0) { int k = __builtin_ctzll(b0); b0 &= b0 - 1; s_list[tid][n++] = (unsigned char)k; }
        while (b1) { int k = __builtin_ctzll(b1); b1 &= b1 - 1; s_list[tid][n++] = (unsigned char)(64 + k); }
        s_cnt[tid] = n;
    }
    __syncthreads();

    // ---- per-(tile,entry) PAIR-activity mask; writes packed u32 list ----
    // u over tile = u_c +- R exactly (linear). Edge inactive: u_max < -TH
    // (factor within 2^-TH of 1). Pair active if EITHER edge active (active
    // pairs are computed exactly in raster -> no extra error). Dead slot:
    // any edge u_min > +TH (cov <= 2^-TH over tile).
    // Entry: slot | pairmask<<8 (6b) | dead<<14.
    {
        unsigned int* dstl = g_list + (size_t)frame * (256 * NN);
        const float DY = 0.5f / HH, DX = 15.5f / WW;
        for (int idx = tid; idx < 256 * NN; idx += STPB) {  // 32 iters
            int tile = idx >> 7;
            int i    = idx & (NN - 1);
            if (i >= s_cnt[tile]) continue;
            int slot = s_list[tile][i];
            int rp = tile >> 2, qq = tile & 3;
            float gyc = (2 * rp + 1) * (1.0f / HH);
            float gxc = (32 * qq + 16) * (1.0f / WW);
            unsigned pm = 0;
            bool dead = false;
            #pragma unroll
            for (int k = 0; k < KK; k++) {
                float A = s_coef[slot][k];
                float B = s_coef[slot][12 + k];
                float C = s_coef[slot][24 + k];
                float u = fmaf(A, gyc, fmaf(B, gxc, C));
                float R = fmaf(__builtin_fabsf(A), DY, __builtin_fabsf(B) * DX);
                if (u + R > -MASK_TH) pm |= (1u << (k >> 1));
                if (u - R >  MASK_TH) dead = true;
            }
            dstl[tile * NN + i] = (unsigned)slot | (pm << 8) | (dead ? (1u << 14) : 0u);
        }
    }

    // ---- copy out (LDS stride 41 -> global stride 40) ----
    {
        float* dstc = g_coef + (size_t)frame * (NN * COEF_STRIDE);
        for (int i = tid; i < NN * COEF_STRIDE; i += STPB) {
            int slot = i / COEF_STRIDE;
            int k    = i - slot * COEF_STRIDE;
            dstc[i] = s_coef[slot][k];
        }
        if (tid < 256) g_cnt[frame * 256 + tid] = s_cnt[tid];
    }
}

struct F3 { float x, y, z; };

__global__ __launch_bounds__(RTPB) void raster_kernel(
    const float* __restrict__ g_coef,
    const int* __restrict__ g_cnt,
    const unsigned int* __restrict__ g_list,
    float* __restrict__ out)
{
    __shared__ unsigned int s_wlist[4][NN];   // 2 KB

    const int tid   = threadIdx.x;
    const int wv    = __builtin_amdgcn_readfirstlane(tid >> 6);
    const int lane  = tid & 63;
    const int frame = blockIdx.y;
    const int tile  = blockIdx.x * 4 + wv;  // 0..255
    const int rp    = tile >> 2;            // row pair
    const int q     = tile & 3;             // x quarter

    // stage this wave's survivor list into its private LDS strip
    const unsigned int* lst = g_list + ((size_t)frame * 256 + tile) * NN;
    ((uint2*)&s_wlist[wv][0])[lane] = ((const uint2*)lst)[lane];
    const int cnt = g_cnt[frame * 256 + tile]; // uniform -> s_load

    const int lx  = lane & 31, ly = lane >> 5;
    const int px  = q * 32 + lx;
    const int row = rp * 2 + ly;
    const float gy = (row + 0.5f) * (1.0f / HH);
    const float gx = (px  + 0.5f) * (1.0f / WW);
    const f2 gy2 = {gy, gy};
    const f2 gx2 = {gx, gx};

    const float* cfr = g_coef + (size_t)frame * (NN * COEF_STRIDE);

    float Tt = 1.f, rr = 0.f, gg = 0.f, bb = 0.f;
    for (int i = 0; i < cnt; i++) {
        unsigned e = (unsigned)__builtin_amdgcn_readfirstlane((int)s_wlist[wv][i]);
        if (e & (1u << 14)) continue;           // dead for this tile (cov<=2^-18)
        int slot = (int)(e & 0xFFu);
        unsigned pm = (e >> 8) & 0x3Fu;
        const float* cf = cfr + slot * COEF_STRIDE; // uniform addr -> scalar loads
        float4 gc = *(const float4*)(cf + 36);      // g, r, g, b (s_load_dwordx4)

        float cov;
        if (pm == 0u) {
            cov = 1.f;                          // all edges saturated inside
        } else {
            const f2* A2 = (const f2*)(cf);
            const f2* B2 = (const f2*)(cf + 12);
            const f2* C2 = (const f2*)(cf + 24);
            // compute ALL pair u's first: loads batch at block entry, and the
            // empty asm pins each u here so nothing sinks into the branches
            // (R10 lesson: sunk loads serialize at ~200cy per bit).
            float ux[6], uy[6];
            #pragma unroll
            for (int j = 0; j < 6; j++) {
                f2 u = __builtin_elementwise_fma(B2[j], gx2,
                         __builtin_elementwise_fma(A2[j], gy2, C2[j]));
                float a_ = u.x, b_ = u.y;
                asm volatile("" : "+v"(a_), "+v"(b_));
                ux[j] = a_; uy[j] = b_;
            }
            float qx = 1.f, qy = 1.f;
            #pragma unroll
            for (int j = 0; j < 6; j++) {
                if (pm & (1u << j)) {           // uniform branch, VALU-only body
                    float sa = fmaxf(ux[j], -100.f);  // exp2 underflow guard
                    float sb = fmaxf(uy[j], -100.f);
                    qx = fmaf(qx, __builtin_amdgcn_exp2f(sa), qx); // *= 1+2^u
                    qy = fmaf(qy, __builtin_amdgcn_exp2f(sb), qy);
                }
            }
            cov = __builtin_amdgcn_rcpf(qx * qy);
        }

        float a = cov * gc.x;
        float w = a * Tt;
        rr = fmaf(w, gc.y, rr);
        gg = fmaf(w, gc.z, gg);
        bb = fmaf(w, gc.w, bb);
        Tt = fmaf(-a, Tt, Tt);

        if (!__any(Tt > 2e-3f)) break;   // residual <= T < 2e-3
    }

    size_t o = ((size_t)frame * (HH * WW) + (size_t)row * WW + px) * 3;
    *(F3*)(out + o) = F3{rr, gg, bb};    // coalesced dwordx3 per row segment
}

extern "C" void kernel_launch(void* const* d_in, const int* in_sizes, int n_in,
                              void* d_out, int out_size, void* d_ws, size_t ws_size,
                              hipStream_t stream) {
    const float* traj   = (const float*)d_in[0];
    const float* colors = (const float*)d_in[1];
    const float* alpha  = (const float*)d_in[2];
    const float* zval   = (const float*)d_in[3];
    const void*  csg    = d_in[4];
    float* out = (float*)d_out;

    const int T = in_sizes[0] / STATE_SZ; // 192

    size_t coef_sz = (size_t)T * NN * COEF_STRIDE * sizeof(float);  // 3.93 MB
    size_t cnt_sz  = (size_t)T * 256 * sizeof(int);                 // 0.20 MB
    float* g_coef = (float*)d_ws;
    int*   g_cnt  = (int*)((char*)d_ws + coef_sz);
    unsigned int* g_list = (unsigned int*)((char*)d_ws + coef_sz + cnt_sz); // 25.2 MB

    setup_kernel<<<T, STPB, 0, stream>>>(traj, colors, alpha, zval, csg,
                                         g_coef, g_cnt, g_list);
    dim3 grid(256 / 4, T); // 64 x 192, wave = one 32x2 tile
    raster_kernel<<<grid, RTPB, 0, stream>>>(g_coef, g_cnt, g_list, out);
}

// Round 3
// 228.037 us; speedup vs baseline: 1.5906x; 1.2486x over previous
//
#include <hip/hip_runtime.h>

// Soft differentiable rasterizer, forward only. Two-kernel structure.
// R11 -> R12: MASK MACHINERY DELETED (R10/R11 post-mortem: SOFT=0.01 gives
// a +-30-50px sigmoid transition band -> per-tile edge masks are dense at
// any tile size; interval cull already removes the deep-outside cases.
// Mask = overhead only: 167us vs R9's 131us raster).
// R12 = R9 structure + two targeted fixes:
// (a) raster: coefficient PREFETCH double-buffer. R9's per-slot chain
//     ds_read_u8 -> readfirstlane -> s_load 40 dwords (~200cy L2) -> compute
//     left ~34% of issue idle (VALUBusy 66%). Load slot i+1's coefs (SGPRs)
//     before slot i's exp2 chain; wait lands under covered latency.
// (b) setup LDS fixes: s_pq padded 12->18 float2 (slot stride 36 words:
//     8-lane groups cover all 8 bank-quads on float4 reads; was stride 24
//     = 8-way conflict). Compaction rewritten wave-cooperative (mbcnt
//     prefix scatter) replacing 256 serial bit-pop threads whose byte
//     writes were 32-way bank-conflicted. csg scan one-wave ballot.
// Design (from R8/R9): 32x2 px tiles, setup cull via per-edge line form,
// pos-first packing, strided line-form loop, raster scalar coefficient
// cache, packed-fp32 sigmoid product, front-to-back T, wave exit T<2e-3.

#define HH 128
#define WW 128
#define NN 128
#define KK 12
#define STPB 1024
#define RTPB 256
#define STATE_SZ (NN * KK * 2 + NN) // 3200
#define CULL_U 15.0f
#define COEF_STRIDE 40              // floats per slot: A[12] B[12] C[12] gc[4]
#define PQ_STRIDE 18                // float2 per slot (padded; 36 words, bank-optimal)

typedef float f2 __attribute__((ext_vector_type(2)));

__global__ __launch_bounds__(STPB) void setup_kernel(
    const float* __restrict__ traj,
    const float* __restrict__ colors,
    const float* __restrict__ alpha,
    const float* __restrict__ zval,
    const void*  __restrict__ csg_raw,
    float* __restrict__ g_coef,         // [T][128][40]
    int* __restrict__ g_cnt,            // [T][256]
    unsigned char* __restrict__ g_list) // [T][256][128]
{
    __shared__ __align__(16) float s_coef[NN][COEF_STRIDE];       // 20.5 KB
    __shared__ __align__(16) float2 s_pq[NN][PQ_STRIDE];          // 18 KB
    __shared__ float s_state[STATE_SZ];                           // 12.8 KB
    __shared__ float s_orient[NN];
    __shared__ float s_z[NN];
    __shared__ int   s_slot2prim[NN];
    __shared__ int   s_npos[NN], s_nneg[NN];
    __shared__ unsigned long long s_qbits[HH][4][2];              // 8 KB
    __shared__ unsigned char s_list[4 * (HH / 2)][NN];            // 32 KB
    __shared__ int s_cnt[4 * (HH / 2)];
    __shared__ int s_mode;

    const int frame = blockIdx.x;
    const int tid   = threadIdx.x;
    const float* st = traj + (size_t)frame * STATE_SZ;

    // ---- stage + csg layout detect (one-wave ballot) + counter init ----
    for (int i = tid; i < STATE_SZ; i += STPB) s_state[i] = st[i];
    if (tid < NN) { s_z[tid] = zval[tid]; s_npos[tid] = 0; s_nneg[tid] = 0; }
    if (tid < 64) {
        unsigned w = (tid < 32) ? ((const unsigned*)csg_raw)[tid] : 0u;
        unsigned long long anyw = __ballot(w > 1u);            // some word not 0/1
        unsigned long long anyb = __ballot((w & 0xFEFEFEFEu) != 0u); // some byte > 1
        if (tid == 0) s_mode = (anyw == 0ull) ? 0 : ((anyb == 0ull) ? 1 : 2);
    }
    __syncthreads();

    // ---- per-prim: orient, g = alpha*sigmoid(alive), z-rank -> slot ----
    if (tid < NN) {
        const int n = tid;
        float area2 = 0.f;
        #pragma unroll
        for (int k = 0; k < KK; k++) {
            int k1 = (k + 1) % KK;
            float v0x = s_state[(n * KK + k)  * 2 + 0];
            float v0y = s_state[(n * KK + k)  * 2 + 1];
            float v1x = s_state[(n * KK + k1) * 2 + 0];
            float v1y = s_state[(n * KK + k1) * 2 + 1];
            area2 += v0x * v1y - v1x * v0y;
        }
        float orient = (area2 > 0.f) ? 1.f : ((area2 < 0.f) ? -1.f : 0.f);
        s_orient[n] = orient;

        float alive = s_state[NN * KK * 2 + n];
        float g = alpha[n] / (1.f + __expf(-alive));

        float zn = s_z[n];
        int rank = 0;
        #pragma unroll 8
        for (int j = 0; j < NN; j++) {
            float zj = s_z[j];
            rank += (zj < zn || (zj == zn && j < n)) ? 1 : 0;
        }
        int slot = (NN - 1) - rank; // slot 0 = frontmost (largest z)
        s_slot2prim[slot] = n;

        int mode = s_mode;
        int sub;
        if (mode == 0)      sub = ((const int*)csg_raw)[n] != 0;
        else if (mode == 1) sub = ((const unsigned char*)csg_raw)[n] != 0;
        else                sub = ((const float*)csg_raw)[n] != 0.f;
        float cs = sub ? 0.f : 1.f;
        s_coef[slot][36] = g;
        s_coef[slot][37] = colors[n * 3 + 0] * cs;
        s_coef[slot][38] = colors[n * 3 + 1] * cs;
        s_coef[slot][39] = colors[n * 3 + 2] * cs;
    }
    __syncthreads();

    // ---- edge coefficients (slot-ordered SoA) ----
    const float QSCALE = 100.0f * 1.4426950408889634f;
    for (int idx = tid; idx < NN * KK; idx += STPB) {
        int slot = idx / KK;
        int k    = idx - slot * KK;
        int n    = s_slot2prim[slot];
        int k1   = (k + 1) % KK;
        float v0x = s_state[(n * KK + k)  * 2 + 0];
        float v0y = s_state[(n * KK + k)  * 2 + 1];
        float v1x = s_state[(n * KK + k1) * 2 + 0];
        float v1y = s_state[(n * KK + k1) * 2 + 1];
        float ex = v1x - v0x, ey = v1y - v0y;
        float q  = -s_orient[n] * QSCALE;
        s_coef[slot][0  + k] = q * ex;                      // A
        s_coef[slot][12 + k] = -q * ey;                     // B
        s_coef[slot][24 + k] = -q * (ex * v0y - ey * v0x);  // C
    }
    __syncthreads();

    // ---- line form per edge: x-constraint t(gy) = Q*gy + P ----
    // B>0: x <= t (+SLACK); B<0: x >= t (stored negated: -x <= -t, +SLACK);
    // B==0: no x-constraint -> neg-bucket entry with t' = +1e30 (never binds).
    // Pos edges packed first (k < npos). STRIDED LOOP (R8 bug: bare if).
    const float SLACK = 0.01f;
    for (int idx = tid; idx < NN * KK; idx += STPB) {
        int slot = idx / KK;
        int k    = idx - slot * KK;
        (void)k;
        float A = s_coef[slot][idx - slot * KK];
        float B = s_coef[slot][12 + (idx - slot * KK)];
        float C = s_coef[slot][24 + (idx - slot * KK)];
        float rcpB = __builtin_amdgcn_rcpf(B);
        float Praw = (CULL_U - C) * rcpB;
        float Qraw = -A * rcpB;
        if (B > 0.f) {
            int i = atomicAdd(&s_npos[slot], 1);
            s_pq[slot][i] = make_float2(Qraw, Praw + SLACK);
        } else if (B < 0.f) {
            int i = atomicAdd(&s_nneg[slot], 1);
            s_pq[slot][(KK - 1) - i] = make_float2(-Qraw, -Praw + SLACK);
        } else { // B == 0: x-independent edge; conservatively no constraint
            int i = atomicAdd(&s_nneg[slot], 1);
            s_pq[slot][(KK - 1) - i] = make_float2(0.f, 1e30f);
        }
    }
    __syncthreads();

    // ---- joint interval cull; 4 x-quarter keep masks per row ----
    // wave covers one row (r const) x 64 slots (s = s0 + lane).
    // s_pq slot stride = 36 words -> float4 reads conflict-optimal (8cy floor).
    const float GX_LO = 0.5f / WW;
    const float GX_HI = (WW - 0.5f) / WW;
    for (int j = 0; j < (HH * NN) / STPB; j++) {     // 16 iters
        int idx = j * STPB + tid;
        int r = idx >> 7, s = idx & (NN - 1);
        float gyr = (r + 0.5f) * (1.0f / HH);
        int npos = s_npos[s];
        const float4* pq4 = (const float4*)&s_pq[s][0];
        float y1 = 1e30f, y2 = 1e30f;
        #pragma unroll
        for (int h = 0; h < KK / 2; h++) {
            float4 v = pq4[h];                       // {Q,P,Q,P}
            int k0 = 2 * h, k1 = 2 * h + 1;
            float t0 = fmaf(v.x, gyr, v.y);
            float t1 = fmaf(v.z, gyr, v.w);
            bool p0 = k0 < npos, p1 = k1 < npos;
            y1 = fminf(y1, p0 ? t0 : 1e30f);
            y2 = fminf(y2, p0 ? 1e30f : t0);
            y1 = fminf(y1, p1 ? t1 : 1e30f);
            y2 = fminf(y2, p1 ? 1e30f : t1);
        }
        float xhi = fminf(y1, GX_HI);
        float xlo = fmaxf(-y2, GX_LO);
        bool ne = (xlo <= xhi);
        #pragma unroll
        for (int q = 0; q < 4; q++) {
            float qlo = (q * 32 + 0.5f) * (1.0f / WW);
            float qhi = (q * 32 + 31.5f) * (1.0f / WW);
            unsigned long long m = __ballot(ne && (xlo <= qhi) && (xhi >= qlo));
            if ((tid & 63) == 0) s_qbits[r][q][(s >= 64) ? 1 : 0] = m;
        }
    }
    __syncthreads();

    // ---- compaction: wave-cooperative mbcnt prefix scatter ----
    // wave wvS handles tiles [wvS*16, wvS*16+16); lane = slot candidate.
    // Replaces serial per-thread bit-pop (32-way conflicted byte writes).
    {
        int wvS = tid >> 6;
        int ln  = tid & 63;
        for (int it = 0; it < 16; it++) {
            int t = wvS * 16 + it;
            int rp = t >> 2, qq = t & 3;
            unsigned long long b0 = s_qbits[2 * rp][qq][0] | s_qbits[2 * rp + 1][qq][0];
            unsigned long long b1 = s_qbits[2 * rp][qq][1] | s_qbits[2 * rp + 1][qq][1];
            int c0 = __popcll(b0);
            int p0 = __builtin_amdgcn_mbcnt_hi((unsigned)(b0 >> 32),
                     __builtin_amdgcn_mbcnt_lo((unsigned)b0, 0));
            int p1 = __builtin_amdgcn_mbcnt_hi((unsigned)(b1 >> 32),
                     __builtin_amdgcn_mbcnt_lo((unsigned)b1, 0));
            if ((b0 >> ln) & 1ull) s_list[t][p0]      = (unsigned char)ln;
            if ((b1 >> ln) & 1ull) s_list[t][c0 + p1] = (unsigned char)(64 + ln);
            if (ln == 0) s_cnt[t] = c0 + __popcll(b1);
        }
    }
    __syncthreads();

    // ---- copy out ----
    {
        float* dstc = g_coef + (size_t)frame * (NN * COEF_STRIDE);
        const float* srcc = &s_coef[0][0];
        for (int i = tid; i < NN * COEF_STRIDE; i += STPB) dstc[i] = srcc[i];
        if (tid < 256) g_cnt[frame * 256 + tid] = s_cnt[tid];
        unsigned int* dstl = (unsigned int*)(g_list + (size_t)frame * (256 * NN));
        const unsigned int* srcl = (const unsigned int*)&s_list[0][0];
        for (int i = tid; i < (256 * NN) / 4; i += STPB) dstl[i] = srcl[i];
    }
}

struct F3 { float x, y, z; };

__global__ __launch_bounds__(RTPB) void raster_kernel(
    const float* __restrict__ g_coef,
    const int* __restrict__ g_cnt,
    const unsigned char* __restrict__ g_list,
    float* __restrict__ out)
{
    __shared__ unsigned char s_wlist[4][NN];

    const int tid   = threadIdx.x;
    const int wv    = __builtin_amdgcn_readfirstlane(tid >> 6);
    const int lane  = tid & 63;
    const int frame = blockIdx.y;
    const int tile  = blockIdx.x * 4 + wv;  // 0..255
    const int rp    = tile >> 2;            // row pair
    const int q     = tile & 3;             // x quarter

    // stage this wave's survivor list into its private LDS strip
    const unsigned char* lst = g_list + ((size_t)frame * 256 + tile) * NN;
    if (lane < NN / 4) {
        ((unsigned int*)&s_wlist[wv][0])[lane] = ((const unsigned int*)lst)[lane];
    }
    const int cnt = g_cnt[frame * 256 + tile]; // uniform -> s_load

    const int lx  = lane & 31, ly = lane >> 5;
    const int px  = q * 32 + lx;
    const int row = rp * 2 + ly;
    const float gy = (row + 0.5f) * (1.0f / HH);
    const float gx = (px  + 0.5f) * (1.0f / WW);
    const f2 gy2 = {gy, gy};
    const f2 gx2 = {gx, gx};
    const f2 lo2 = {-100.f, -100.f};

    const float* cfr = g_coef + (size_t)frame * (NN * COEF_STRIDE);

    float Tt = 1.f, rr = 0.f, gg = 0.f, bb = 0.f;
    if (cnt > 0) {
        // prefetch slot 0's coefficients (SGPR-resident: uniform address)
        int sl_n = __builtin_amdgcn_readfirstlane((int)s_wlist[wv][0]);
        const float* cfn = cfr + sl_n * COEF_STRIDE;
        f2 An[6], Bn[6], Cn[6]; float4 gcn;
        #pragma unroll
        for (int j = 0; j < 6; j++) {
            An[j] = ((const f2*)(cfn     ))[j];
            Bn[j] = ((const f2*)(cfn + 12))[j];
            Cn[j] = ((const f2*)(cfn + 24))[j];
        }
        gcn = *(const float4*)(cfn + 36);

        for (int i = 0; i < cnt; i++) {
            // rotate prefetched -> current
            f2 A[6], B[6], C[6]; float4 gc = gcn;
            #pragma unroll
            for (int j = 0; j < 6; j++) { A[j] = An[j]; B[j] = Bn[j]; C[j] = Cn[j]; }

            // issue next iteration's loads BEFORE the exp2 chain (clamped idx)
            int inx = (i + 1 < cnt) ? (i + 1) : i;
            sl_n = __builtin_amdgcn_readfirstlane((int)s_wlist[wv][inx]);
            cfn = cfr + sl_n * COEF_STRIDE;
            #pragma unroll
            for (int j = 0; j < 6; j++) {
                An[j] = ((const f2*)(cfn     ))[j];
                Bn[j] = ((const f2*)(cfn + 12))[j];
                Cn[j] = ((const f2*)(cfn + 24))[j];
            }
            gcn = *(const float4*)(cfn + 36);

            // packed sigmoid product over 12 edges
            f2 qv = {1.f, 1.f};
            #pragma unroll
            for (int j = 0; j < 6; j++) {
                f2 u = __builtin_elementwise_fma(B[j], gx2,
                         __builtin_elementwise_fma(A[j], gy2, C[j]));
                u = __builtin_elementwise_max(u, lo2);   // exp2(-big)=0 exactly -> inf*0 NaN guard
                f2 e;
                e.x = __builtin_amdgcn_exp2f(u.x);
                e.y = __builtin_amdgcn_exp2f(u.y);
                qv = __builtin_elementwise_fma(qv, e, qv); // q *= 1 + 2^u
            }
            float cov = __builtin_amdgcn_rcpf(qv.x * qv.y);

            float a = cov * gc.x;
            float w = a * Tt;
            rr = fmaf(w, gc.y, rr);
            gg = fmaf(w, gc.z, gg);
            bb = fmaf(w, gc.w, bb);
            Tt = fmaf(-a, Tt, Tt);

            if (!__any(Tt > 2e-3f)) break;   // residual <= T < 2e-3
        }
    }

    size_t o = ((size_t)frame * (HH * WW) + (size_t)row * WW + px) * 3;
    *(F3*)(out + o) = F3{rr, gg, bb};    // coalesced dwordx3 per row segment
}

extern "C" void kernel_launch(void* const* d_in, const int* in_sizes, int n_in,
                              void* d_out, int out_size, void* d_ws, size_t ws_size,
                              hipStream_t stream) {
    const float* traj   = (const float*)d_in[0];
    const float* colors = (const float*)d_in[1];
    const float* alpha  = (const float*)d_in[2];
    const float* zval   = (const float*)d_in[3];
    const void*  csg    = d_in[4];
    float* out = (float*)d_out;

    const int T = in_sizes[0] / STATE_SZ; // 192

    size_t coef_sz = (size_t)T * NN * COEF_STRIDE * sizeof(float); // 3.93 MB
    size_t cnt_sz  = (size_t)T * 256 * sizeof(int);                // 0.20 MB
    float* g_coef = (float*)d_ws;
    int*   g_cnt  = (int*)((char*)d_ws + coef_sz);
    unsigned char* g_list = (unsigned char*)d_ws + coef_sz + cnt_sz; // 6.29 MB

    setup_kernel<<<T, STPB, 0, stream>>>(traj, colors, alpha, zval, csg,
                                         g_coef, g_cnt, g_list);
    dim3 grid(256 / 4, T); // 64 x 192, wave = one 32x2 tile
    raster_kernel<<<grid, RTPB, 0, stream>>>(g_coef, g_cnt, g_list, out);
}